// Round 8
// baseline (1455.024 us; speedup 1.0000x reference)
//
#include <hip/hip_runtime.h>
#include <hip/hip_cooperative_groups.h>

// Sinkhorn divergence (geomloss 'sinkhorn', p=2, blur=0.05, diameter=4, scaling=0.5, debias)
// B=2, N=M=4096, D=3, fp32.
// R8: R7's cooperative mega-kernel made fail-safe. sinkhorn_iters(K,L0,L1,doSync) runs a
// range of iterations; coop path = ONE launch (0..11) with threadfence+grid.sync between
// iterations; host CHECKS the coop launch return code and falls back to 11 plain launches
// (identical kernel, doSync=0) on any error. Register-slimmed (no prefetch, R4 inner loop)
// to protect 2-blocks/CU co-residency. MFMA K-slot packing unchanged (R3-R6, absmax 0).

namespace cg = cooperative_groups;

typedef __attribute__((ext_vector_type(8))) short short8;
typedef __attribute__((ext_vector_type(8))) __bf16 bf16x8;
typedef __attribute__((ext_vector_type(4))) float f32x4;
typedef __attribute__((ext_vector_type(2))) float f32x2;

#define NPT 4096
#define BLOCK 512
#define COLS 1024           // columns per block (one part)
#define NPARTS 4
#define ROWS_PER_BLOCK 256  // 8 waves x 2 rowsets x 16
#define NRC 16              // rowchunks
#define GRID (8 * NPARTS * NRC)   // 512
#define NITER 11
#define EXP2 __builtin_amdgcn_exp2f
#define LOG2 __builtin_amdgcn_logf
#define KLOG2E 1.4426950408889634f
#define KLN2 0.6931471805599453f

__device__ inline unsigned short f2bf(float f) {
  unsigned u = __float_as_uint(f);
  return (unsigned short)((u + 0x7FFF + ((u >> 16) & 1)) >> 16);
}
__device__ inline float bf2f(unsigned short h) {
  return __uint_as_float(((unsigned)h) << 16);
}

struct KArgs {
  const float* x;
  const float* y;
  float2* P0;
  float2* P1;
  float* F0;
  float* F1;
};

__device__ __constant__ float c_epsL[NITER] = {16.0f, 16.0f, 16.0f, 4.0f, 1.0f, 0.25f,
                                               0.0625f, 0.015625f, 0.00390625f, 0.0025f,
                                               0.0025f};
__device__ __constant__ int c_avgL[NITER] = {0, 1, 1, 1, 1, 1, 1, 1, 1, 1, 0};

// merge 16 values into running (m,s): packed max tree + packed sub/sum, 17 exp2
__device__ inline void lse_merge16(float& m, float& s,
                                   f32x4 c0, f32x4 c1, f32x4 c2, f32x4 c3) {
  f32x2 p0 = {c0.x, c0.y}, p1 = {c0.z, c0.w};
  f32x2 p2 = {c1.x, c1.y}, p3 = {c1.z, c1.w};
  f32x2 p4 = {c2.x, c2.y}, p5 = {c2.z, c2.w};
  f32x2 p6 = {c3.x, c3.y}, p7 = {c3.z, c3.w};
  f32x2 q0 = __builtin_elementwise_max(p0, p1);
  f32x2 q1 = __builtin_elementwise_max(p2, p3);
  f32x2 q2 = __builtin_elementwise_max(p4, p5);
  f32x2 q3 = __builtin_elementwise_max(p6, p7);
  f32x2 r0 = __builtin_elementwise_max(q0, q1);
  f32x2 r1 = __builtin_elementwise_max(q2, q3);
  f32x2 rm = __builtin_elementwise_max(r0, r1);
  float cm = fmaxf(rm.x, rm.y);
  float mn = fmaxf(m, cm);
  float sc = EXP2(m - mn);                 // m=-inf first iter -> 0
  f32x2 mn2 = {mn, mn};
  f32x2 sa, sb, d;
  d = p0 - mn2; sa  = (f32x2){EXP2(d.x), EXP2(d.y)};
  d = p1 - mn2; sb  = (f32x2){EXP2(d.x), EXP2(d.y)};
  d = p2 - mn2; sa += (f32x2){EXP2(d.x), EXP2(d.y)};
  d = p3 - mn2; sb += (f32x2){EXP2(d.x), EXP2(d.y)};
  d = p4 - mn2; sa += (f32x2){EXP2(d.x), EXP2(d.y)};
  d = p5 - mn2; sb += (f32x2){EXP2(d.x), EXP2(d.y)};
  d = p6 - mn2; sa += (f32x2){EXP2(d.x), EXP2(d.y)};
  d = p7 - mn2; sb += (f32x2){EXP2(d.x), EXP2(d.y)};
  sa += sb;
  s = fmaf(s, sc, sa.x + sa.y);
  m = mn;
}

__global__ __launch_bounds__(BLOCK, 4) void sinkhorn_iters(KArgs K, int L0, int L1,
                                                           int doSync) {
  // frag[0..1023]=k0..7 per column, frag[1024..2047]=k8..15, frag[2048..2111]=zeros
  __shared__ short8 frag[2 * COLS + 64];

  const int bid  = blockIdx.x;
  const int tbl  = bid >> 6;          // 0..7 = task*2+batch
  const int task = tbl >> 1, batch = tbl & 1;
  const int rem  = bid & 63;
  const int part = rem >> 4;          // 0..3
  const int rc   = rem & 15;          // 0..15

  const float* rowsA[4] = {K.x, K.y, K.x, K.y};  // b_x<-C_xy, a_y<-C_yx, a_x<-C_xx, b_y<-C_yy
  const float* colsA[4] = {K.y, K.x, K.x, K.y};
  const float* xp = rowsA[task] + batch * NPT * 3;
  const float* yp = colsA[task] + batch * NPT * 3;
  const int pidxA[4] = {1, 0, 2, 3};
  const int tP = pidxA[task] * 2 + batch;

  const float hc = -8.317766166719343f;   // -ln(4096)
  const int lane = threadIdx.x & 63;
  const int wave = threadIdx.x >> 6;      // 0..7
  const int q    = lane >> 4;

  // ---- build B fragments once (x side is iteration-invariant), 2 rowsets ----
  const int rowbase = rc * ROWS_PER_BLOCK + wave * 32;
  bf16x8 Bf[2];
#pragma unroll
  for (int rs = 0; rs < 2; ++rs) {
    int i = rowbase + rs * 16 + (lane & 15);
    float X0 = xp[3 * i], X1 = xp[3 * i + 1], X2 = xp[3 * i + 2];
    unsigned short xh0 = f2bf(X0), xh1 = f2bf(X1), xh2 = f2bf(X2);
    unsigned short xl0 = f2bf(X0 - bf2f(xh0));
    unsigned short xl1 = f2bf(X1 - bf2f(xh1));
    unsigned short xl2 = f2bf(X2 - bf2f(xh2));
    short8 bb = (short8)0;
    if (q == 0) {
      short8 t = {(short)xh0, (short)xh1, (short)xh2,
                  (short)xh0, (short)xh1, (short)xh2,
                  (short)xl0, (short)xl1};
      bb = t;
    } else if (q == 1) {
      short8 t = {(short)xl2, (short)0x3F80, (short)0x3F80, (short)0x3F80,
                  (short)xl0, (short)xl1, (short)xl2, 0};
      bb = t;
    }
    Bf[rs] = __builtin_bit_cast(bf16x8, bb);
  }

  // zero-pad region for lanes >= 32 (reads k16..31 operands as 0)
  if (threadIdx.x < 64) frag[2 * COLS + threadIdx.x] = (short8)0;

  float2* Pbuf[2] = {K.P0, K.P1};
  float*  Fbuf[2] = {K.F0, K.F1};

  for (int L = L0; L < L1; ++L) {
    const float eps = c_epsL[L];
    const float inv_eps = 1.0f / eps;
    const float sY = inv_eps * KLOG2E;
    const float2* Pprev = Pbuf[(L + 1) & 1];
    float2*       Pcur  = Pbuf[L & 1];
    const float*  Fprev = Fbuf[(L + 1) & 1];
    float*        Fcur  = Fbuf[L & 1];
    const float epsPrev = (L > 0) ? c_epsL[L - 1] : 1.0f;
    const int usePot  = (L > 0);
    const int avgPrev = (L > 0) ? c_avgL[L - 1] : 0;

    // ---- staging: finalize prev-iter potentials + build column A-fragments ----
#pragma unroll
    for (int c = 0; c < COLS / BLOCK; ++c) {
      int jl = threadIdx.x + c * BLOCK;
      int j  = part * COLS + jl;
      float y0 = yp[3 * j], y1 = yp[3 * j + 1], y2 = yp[3 * j + 2];
      float y2n = 0.5f * (y0 * y0 + y1 * y1 + y2 * y2);
      float pot = 0.0f;
      if (usePot) {
        float2 q0v = Pprev[(tP * NPARTS + 0) * NPT + j];
        float2 q1v = Pprev[(tP * NPARTS + 1) * NPT + j];
        float2 q2v = Pprev[(tP * NPARTS + 2) * NPT + j];
        float2 q3v = Pprev[(tP * NPARTS + 3) * NPT + j];
        float M = fmaxf(fmaxf(q0v.x, q1v.x), fmaxf(q2v.x, q3v.x));
        float S = q0v.y * EXP2(q0v.x - M) + q1v.y * EXP2(q1v.x - M)
                + q2v.y * EXP2(q2v.x - M) + q3v.y * EXP2(q3v.x - M);
        float Lv = M + LOG2(S);
        float r = y2n - epsPrev * KLN2 * Lv;
        if (avgPrev) r = 0.5f * (Fprev[tP * NPT + j] + r);
        pot = r;
        if (rc == 0) Fcur[tP * NPT + j] = pot;
      }
      float T = (hc + (pot - y2n) * inv_eps) * KLOG2E;
      float s0 = y0 * sY, s1 = y1 * sY, s2 = y2 * sY;
      unsigned short yh0 = f2bf(s0), yh1 = f2bf(s1), yh2 = f2bf(s2);
      unsigned short yl0 = f2bf(s0 - bf2f(yh0));
      unsigned short yl1 = f2bf(s1 - bf2f(yh1));
      unsigned short yl2 = f2bf(s2 - bf2f(yh2));
      unsigned short Th = f2bf(T);
      float tr = T - bf2f(Th);
      unsigned short Tm = f2bf(tr);
      tr -= bf2f(Tm);
      unsigned short Tl = f2bf(tr);
      short8 h0 = {(short)yh0, (short)yh1, (short)yh2,
                   (short)yl0, (short)yl1, (short)yl2,
                   (short)yh0, (short)yh1};
      short8 h1 = {(short)yh2, (short)Th, (short)Tm, (short)Tl,
                   (short)yl0, (short)yl1, (short)yl2, 0};
      frag[jl] = h0;
      frag[COLS + jl] = h1;
    }
    __syncthreads();

    // ---- inner loop: 4 col-tiles (64 cols)/iter, 8 MFMAs, 2 merge16 ----
    int idx = ((q == 0) ? 0 : (q == 1) ? COLS : 2 * COLS) + (lane & 15);
    const int stride = (lane < 32) ? 64 : 0;
    float m0 = -__builtin_inff(), s0_ = 0.0f;
    float m1 = -__builtin_inff(), s1_ = 0.0f;

#pragma unroll 4
    for (int jt = 0; jt < COLS / 64; ++jt) {
      short8 as0 = frag[idx];
      short8 as1 = frag[idx + 16];
      short8 as2 = frag[idx + 32];
      short8 as3 = frag[idx + 48];
      idx += stride;
      bf16x8 A0 = __builtin_bit_cast(bf16x8, as0);
      bf16x8 A1 = __builtin_bit_cast(bf16x8, as1);
      bf16x8 A2 = __builtin_bit_cast(bf16x8, as2);
      bf16x8 A3 = __builtin_bit_cast(bf16x8, as3);
      const f32x4 Z = {0.0f, 0.0f, 0.0f, 0.0f};
      f32x4 c00 = __builtin_amdgcn_mfma_f32_16x16x32_bf16(A0, Bf[0], Z, 0, 0, 0);
      f32x4 c01 = __builtin_amdgcn_mfma_f32_16x16x32_bf16(A1, Bf[0], Z, 0, 0, 0);
      f32x4 c02 = __builtin_amdgcn_mfma_f32_16x16x32_bf16(A2, Bf[0], Z, 0, 0, 0);
      f32x4 c03 = __builtin_amdgcn_mfma_f32_16x16x32_bf16(A3, Bf[0], Z, 0, 0, 0);
      f32x4 c10 = __builtin_amdgcn_mfma_f32_16x16x32_bf16(A0, Bf[1], Z, 0, 0, 0);
      f32x4 c11 = __builtin_amdgcn_mfma_f32_16x16x32_bf16(A1, Bf[1], Z, 0, 0, 0);
      f32x4 c12 = __builtin_amdgcn_mfma_f32_16x16x32_bf16(A2, Bf[1], Z, 0, 0, 0);
      f32x4 c13 = __builtin_amdgcn_mfma_f32_16x16x32_bf16(A3, Bf[1], Z, 0, 0, 0);
      lse_merge16(m0, s0_, c00, c01, c02, c03);
      lse_merge16(m1, s1_, c10, c11, c12, c13);
    }

    // ---- cross-quad merge (xor 16, xor 32) + store partials ----
#pragma unroll
    for (int rs = 0; rs < 2; ++rs) {
      float m = rs ? m1 : m0;
      float s = rs ? s1_ : s0_;
#pragma unroll
      for (int off = 16; off <= 32; off <<= 1) {
        float mo = __shfl_xor(m, off, 64);
        float so = __shfl_xor(s, off, 64);
        float mn = fmaxf(m, mo);
        s = s * EXP2(m - mn) + so * EXP2(mo - mn);
        m = mn;
      }
      if (lane < 16) {
        int i = rowbase + rs * 16 + lane;
        Pcur[(tbl * NPARTS + part) * NPT + i] = make_float2(m, s);
      }
    }

    if (doSync && (L + 1 < L1)) {
      __threadfence();
      cg::this_grid().sync();
      __syncthreads();
    } else {
      __syncthreads();   // protect frag reuse across L in same launch (no-op last iter)
    }
  }
}

// reduce1: finalize last-iter partials, per-row contribution, per-block partial sums
__global__ __launch_bounds__(256) void reduce1(const float2* P, float* R1) {
  int u = blockIdx.x * 256 + threadIdx.x;   // 0..8191
  int b = u >> 12, i = u & 4095;
  float Ls[4];
#pragma unroll
  for (int t = 0; t < 4; ++t) {
    int tbl = t * 2 + b;
    float2 q0 = P[(tbl * NPARTS + 0) * NPT + i];
    float2 q1 = P[(tbl * NPARTS + 1) * NPT + i];
    float2 q2 = P[(tbl * NPARTS + 2) * NPT + i];
    float2 q3 = P[(tbl * NPARTS + 3) * NPT + i];
    float M = fmaxf(fmaxf(q0.x, q1.x), fmaxf(q2.x, q3.x));
    float S = q0.y * EXP2(q0.x - M) + q1.y * EXP2(q1.x - M)
            + q2.y * EXP2(q2.x - M) + q3.y * EXP2(q3.x - M);
    Ls[t] = M + LOG2(S);
  }
  // (b_x - a_x) + (a_y - b_y) = -eps*ln2*((L0 - L2) + (L1 - L3))
  float acc = (Ls[0] - Ls[2]) + (Ls[1] - Ls[3]);
#pragma unroll
  for (int off = 32; off >= 1; off >>= 1) acc += __shfl_xor(acc, off, 64);
  __shared__ float red[4];
  int wave = threadIdx.x >> 6, lane = threadIdx.x & 63;
  if (lane == 0) red[wave] = acc;
  __syncthreads();
  if (threadIdx.x == 0)
    R1[blockIdx.x] = red[0] + red[1] + red[2] + red[3];
}

__global__ __launch_bounds__(64) void reduce2(const float* R1, float* out) {
  float a = (threadIdx.x < 32) ? R1[threadIdx.x] : 0.0f;
#pragma unroll
  for (int off = 32; off >= 1; off >>= 1) a += __shfl_xor(a, off, 64);
  if (threadIdx.x == 0)
    out[0] = a * (-0.0025f * KLN2 / 4096.0f);
}

extern "C" void kernel_launch(void* const* d_in, const int* in_sizes, int n_in,
                              void* d_out, int out_size, void* d_ws, size_t ws_size,
                              hipStream_t stream) {
  const float* x = (const float*)d_in[0];   // true_data
  const float* y = (const float*)d_in[1];   // particles
  float* out = (float*)d_out;
  float* W = (float*)d_ws;

  // partials: 8 tbl x 4 parts x 4096 x float2 = 1 MB per set
  KArgs K;
  K.x = x; K.y = y;
  K.P0 = (float2*)W;
  K.P1 = (float2*)(W + 262144);
  K.F0 = W + 524288;
  K.F1 = W + 557056;
  float* R1buf = W + 589824;                // 32 floats

  // --- try cooperative mega-launch; fall back to 11 plain launches on ANY error ---
  int L0 = 0, L1 = NITER, doSync = 1;
  void* kargs[] = { (void*)&K, (void*)&L0, (void*)&L1, (void*)&doSync };
  hipError_t cerr = hipLaunchCooperativeKernel((const void*)sinkhorn_iters,
                                               dim3(GRID), dim3(BLOCK), kargs, 0, stream);
  if (cerr != hipSuccess) {
    for (int L = 0; L < NITER; ++L)
      sinkhorn_iters<<<dim3(GRID), dim3(BLOCK), 0, stream>>>(K, L, L + 1, 0);
  }
  // last iteration L=10 wrote Pbuf[10&1] = P0 (both paths)
  reduce1<<<32, 256, 0, stream>>>(K.P0, R1buf);
  reduce2<<<1, 64, 0, stream>>>(R1buf, out);
}

// Round 9
// 356.098 us; speedup vs baseline: 4.0860x; 4.0860x over previous
//
#include <hip/hip_runtime.h>

// Sinkhorn divergence (geomloss 'sinkhorn', p=2, blur=0.05, diameter=4, scaling=0.5, debias)
// B=2, N=M=4096, D=3, fp32.
// R9: trans-pipe is the wall (R8 PMC: VALUBusy-time 209us total, exp2@~16cyc/wave64
// dominates; MFMA 2.6%, LDS conflicts 0). Add peakedness skip: chunk max cm comes free
// from the pk_max tree; wave-uniform branch skips the 17-exp2 block when no lane has
// cm > m - 27 (contribution < 2^-27 relative -- invisible vs 8.4e-4 threshold).
// Late iterations (eps<=0.25, 6 of 11) should skip >80% of chunks.
// Coop mega-kernel deleted (R8: grid.sync ~100us/sync on MI355X -> 4.4x regression).
// 11 plain launches (R4 structure), MFMA K-slot packing unchanged (absmax 0 since R3).

typedef __attribute__((ext_vector_type(8))) short short8;
typedef __attribute__((ext_vector_type(8))) __bf16 bf16x8;
typedef __attribute__((ext_vector_type(4))) float f32x4;
typedef __attribute__((ext_vector_type(2))) float f32x2;

#define NPT 4096
#define BLOCK 512
#define COLS 1024           // columns per block (one part)
#define NPARTS 4
#define ROWS_PER_BLOCK 256  // 8 waves x 2 rowsets x 16
#define NRC 16              // rowchunks
#define GRID (8 * NPARTS * NRC)   // 512
#define NITER 11
#define SKIP_THR 27.0f      // log2 threshold: skipped chunk contributes < 2^-27 relative
#define EXP2 __builtin_amdgcn_exp2f
#define LOG2 __builtin_amdgcn_logf
#define KLOG2E 1.4426950408889634f
#define KLN2 0.6931471805599453f

__device__ inline unsigned short f2bf(float f) {
  unsigned u = __float_as_uint(f);
  return (unsigned short)((u + 0x7FFF + ((u >> 16) & 1)) >> 16);
}
__device__ inline float bf2f(unsigned short h) {
  return __uint_as_float(((unsigned)h) << 16);
}

struct KArgs {
  const float* x;
  const float* y;
  float2* P0;
  float2* P1;
  float* F0;
  float* F1;
};

__device__ __constant__ float c_epsL[NITER] = {16.0f, 16.0f, 16.0f, 4.0f, 1.0f, 0.25f,
                                               0.0625f, 0.015625f, 0.00390625f, 0.0025f,
                                               0.0025f};
__device__ __constant__ int c_avgL[NITER] = {0, 1, 1, 1, 1, 1, 1, 1, 1, 1, 0};

// merge 16 values into running (m,s), with wave-uniform skip of the exp block
// when no lane can contribute (cm <= m - SKIP_THR for all 64 lanes).
__device__ inline void lse_merge16(float& m, float& s,
                                   f32x4 c0, f32x4 c1, f32x4 c2, f32x4 c3) {
  f32x2 p0 = {c0.x, c0.y}, p1 = {c0.z, c0.w};
  f32x2 p2 = {c1.x, c1.y}, p3 = {c1.z, c1.w};
  f32x2 p4 = {c2.x, c2.y}, p5 = {c2.z, c2.w};
  f32x2 p6 = {c3.x, c3.y}, p7 = {c3.z, c3.w};
  f32x2 q0 = __builtin_elementwise_max(p0, p1);
  f32x2 q1 = __builtin_elementwise_max(p2, p3);
  f32x2 q2 = __builtin_elementwise_max(p4, p5);
  f32x2 q3 = __builtin_elementwise_max(p6, p7);
  f32x2 r0 = __builtin_elementwise_max(q0, q1);
  f32x2 r1 = __builtin_elementwise_max(q2, q3);
  f32x2 rm = __builtin_elementwise_max(r0, r1);
  float cm = fmaxf(rm.x, rm.y);
  if (__any(cm > m - SKIP_THR)) {
    float mn = fmaxf(m, cm);
    float sc = EXP2(m - mn);               // m=-inf first chunk -> 0
    f32x2 mn2 = {mn, mn};
    f32x2 sa, sb, d;
    d = p0 - mn2; sa  = (f32x2){EXP2(d.x), EXP2(d.y)};
    d = p1 - mn2; sb  = (f32x2){EXP2(d.x), EXP2(d.y)};
    d = p2 - mn2; sa += (f32x2){EXP2(d.x), EXP2(d.y)};
    d = p3 - mn2; sb += (f32x2){EXP2(d.x), EXP2(d.y)};
    d = p4 - mn2; sa += (f32x2){EXP2(d.x), EXP2(d.y)};
    d = p5 - mn2; sb += (f32x2){EXP2(d.x), EXP2(d.y)};
    d = p6 - mn2; sa += (f32x2){EXP2(d.x), EXP2(d.y)};
    d = p7 - mn2; sb += (f32x2){EXP2(d.x), EXP2(d.y)};
    sa += sb;
    s = fmaf(s, sc, sa.x + sa.y);
    m = mn;
  }
  // else: every lane's 16 values are < m - 27 -> contribution negligible, skip.
}

__global__ __launch_bounds__(BLOCK, 4) void sinkhorn_iters(KArgs K, int L0, int L1) {
  // frag[0..1023]=k0..7 per column, frag[1024..2047]=k8..15, frag[2048..2111]=zeros
  __shared__ short8 frag[2 * COLS + 64];

  const int bid  = blockIdx.x;
  const int tbl  = bid >> 6;          // 0..7 = task*2+batch
  const int task = tbl >> 1, batch = tbl & 1;
  const int rem  = bid & 63;
  const int part = rem >> 4;          // 0..3
  const int rc   = rem & 15;          // 0..15

  const float* rowsA[4] = {K.x, K.y, K.x, K.y};  // b_x<-C_xy, a_y<-C_yx, a_x<-C_xx, b_y<-C_yy
  const float* colsA[4] = {K.y, K.x, K.x, K.y};
  const float* xp = rowsA[task] + batch * NPT * 3;
  const float* yp = colsA[task] + batch * NPT * 3;
  const int pidxA[4] = {1, 0, 2, 3};
  const int tP = pidxA[task] * 2 + batch;

  const float hc = -8.317766166719343f;   // -ln(4096)
  const int lane = threadIdx.x & 63;
  const int wave = threadIdx.x >> 6;      // 0..7
  const int q    = lane >> 4;

  // ---- build B fragments (x side, iteration-invariant), 2 rowsets ----
  const int rowbase = rc * ROWS_PER_BLOCK + wave * 32;
  bf16x8 Bf[2];
#pragma unroll
  for (int rs = 0; rs < 2; ++rs) {
    int i = rowbase + rs * 16 + (lane & 15);
    float X0 = xp[3 * i], X1 = xp[3 * i + 1], X2 = xp[3 * i + 2];
    unsigned short xh0 = f2bf(X0), xh1 = f2bf(X1), xh2 = f2bf(X2);
    unsigned short xl0 = f2bf(X0 - bf2f(xh0));
    unsigned short xl1 = f2bf(X1 - bf2f(xh1));
    unsigned short xl2 = f2bf(X2 - bf2f(xh2));
    short8 bb = (short8)0;
    if (q == 0) {
      short8 t = {(short)xh0, (short)xh1, (short)xh2,
                  (short)xh0, (short)xh1, (short)xh2,
                  (short)xl0, (short)xl1};
      bb = t;
    } else if (q == 1) {
      short8 t = {(short)xl2, (short)0x3F80, (short)0x3F80, (short)0x3F80,
                  (short)xl0, (short)xl1, (short)xl2, 0};
      bb = t;
    }
    Bf[rs] = __builtin_bit_cast(bf16x8, bb);
  }

  // zero-pad region for lanes >= 32 (reads k16..31 operands as 0)
  if (threadIdx.x < 64) frag[2 * COLS + threadIdx.x] = (short8)0;

  float2* Pbuf[2] = {K.P0, K.P1};
  float*  Fbuf[2] = {K.F0, K.F1};

  for (int L = L0; L < L1; ++L) {
    const float eps = c_epsL[L];
    const float inv_eps = 1.0f / eps;
    const float sY = inv_eps * KLOG2E;
    const float2* Pprev = Pbuf[(L + 1) & 1];
    float2*       Pcur  = Pbuf[L & 1];
    const float*  Fprev = Fbuf[(L + 1) & 1];
    float*        Fcur  = Fbuf[L & 1];
    const float epsPrev = (L > 0) ? c_epsL[L - 1] : 1.0f;
    const int usePot  = (L > 0);
    const int avgPrev = (L > 0) ? c_avgL[L - 1] : 0;

    // ---- staging: finalize prev-iter potentials + build column A-fragments ----
#pragma unroll
    for (int c = 0; c < COLS / BLOCK; ++c) {
      int jl = threadIdx.x + c * BLOCK;
      int j  = part * COLS + jl;
      float y0 = yp[3 * j], y1 = yp[3 * j + 1], y2 = yp[3 * j + 2];
      float y2n = 0.5f * (y0 * y0 + y1 * y1 + y2 * y2);
      float pot = 0.0f;
      if (usePot) {
        float2 q0v = Pprev[(tP * NPARTS + 0) * NPT + j];
        float2 q1v = Pprev[(tP * NPARTS + 1) * NPT + j];
        float2 q2v = Pprev[(tP * NPARTS + 2) * NPT + j];
        float2 q3v = Pprev[(tP * NPARTS + 3) * NPT + j];
        float M = fmaxf(fmaxf(q0v.x, q1v.x), fmaxf(q2v.x, q3v.x));
        float S = q0v.y * EXP2(q0v.x - M) + q1v.y * EXP2(q1v.x - M)
                + q2v.y * EXP2(q2v.x - M) + q3v.y * EXP2(q3v.x - M);
        float Lv = M + LOG2(S);
        float r = y2n - epsPrev * KLN2 * Lv;
        if (avgPrev) r = 0.5f * (Fprev[tP * NPT + j] + r);
        pot = r;
        if (rc == 0) Fcur[tP * NPT + j] = pot;
      }
      float T = (hc + (pot - y2n) * inv_eps) * KLOG2E;
      float s0 = y0 * sY, s1 = y1 * sY, s2 = y2 * sY;
      unsigned short yh0 = f2bf(s0), yh1 = f2bf(s1), yh2 = f2bf(s2);
      unsigned short yl0 = f2bf(s0 - bf2f(yh0));
      unsigned short yl1 = f2bf(s1 - bf2f(yh1));
      unsigned short yl2 = f2bf(s2 - bf2f(yh2));
      unsigned short Th = f2bf(T);
      float tr = T - bf2f(Th);
      unsigned short Tm = f2bf(tr);
      tr -= bf2f(Tm);
      unsigned short Tl = f2bf(tr);
      short8 h0 = {(short)yh0, (short)yh1, (short)yh2,
                   (short)yl0, (short)yl1, (short)yl2,
                   (short)yh0, (short)yh1};
      short8 h1 = {(short)yh2, (short)Th, (short)Tm, (short)Tl,
                   (short)yl0, (short)yl1, (short)yl2, 0};
      frag[jl] = h0;
      frag[COLS + jl] = h1;
    }
    __syncthreads();

    // ---- inner loop: 4 col-tiles (64 cols)/iter, 8 MFMAs, 2 guarded merge16 ----
    int idx = ((q == 0) ? 0 : (q == 1) ? COLS : 2 * COLS) + (lane & 15);
    const int stride = (lane < 32) ? 64 : 0;
    float m0 = -__builtin_inff(), s0_ = 0.0f;
    float m1 = -__builtin_inff(), s1_ = 0.0f;

#pragma unroll 4
    for (int jt = 0; jt < COLS / 64; ++jt) {
      short8 as0 = frag[idx];
      short8 as1 = frag[idx + 16];
      short8 as2 = frag[idx + 32];
      short8 as3 = frag[idx + 48];
      idx += stride;
      bf16x8 A0 = __builtin_bit_cast(bf16x8, as0);
      bf16x8 A1 = __builtin_bit_cast(bf16x8, as1);
      bf16x8 A2 = __builtin_bit_cast(bf16x8, as2);
      bf16x8 A3 = __builtin_bit_cast(bf16x8, as3);
      const f32x4 Z = {0.0f, 0.0f, 0.0f, 0.0f};
      f32x4 c00 = __builtin_amdgcn_mfma_f32_16x16x32_bf16(A0, Bf[0], Z, 0, 0, 0);
      f32x4 c01 = __builtin_amdgcn_mfma_f32_16x16x32_bf16(A1, Bf[0], Z, 0, 0, 0);
      f32x4 c02 = __builtin_amdgcn_mfma_f32_16x16x32_bf16(A2, Bf[0], Z, 0, 0, 0);
      f32x4 c03 = __builtin_amdgcn_mfma_f32_16x16x32_bf16(A3, Bf[0], Z, 0, 0, 0);
      f32x4 c10 = __builtin_amdgcn_mfma_f32_16x16x32_bf16(A0, Bf[1], Z, 0, 0, 0);
      f32x4 c11 = __builtin_amdgcn_mfma_f32_16x16x32_bf16(A1, Bf[1], Z, 0, 0, 0);
      f32x4 c12 = __builtin_amdgcn_mfma_f32_16x16x32_bf16(A2, Bf[1], Z, 0, 0, 0);
      f32x4 c13 = __builtin_amdgcn_mfma_f32_16x16x32_bf16(A3, Bf[1], Z, 0, 0, 0);
      lse_merge16(m0, s0_, c00, c01, c02, c03);
      lse_merge16(m1, s1_, c10, c11, c12, c13);
    }

    // ---- cross-quad merge (xor 16, xor 32) + store partials ----
#pragma unroll
    for (int rs = 0; rs < 2; ++rs) {
      float m = rs ? m1 : m0;
      float s = rs ? s1_ : s0_;
#pragma unroll
      for (int off = 16; off <= 32; off <<= 1) {
        float mo = __shfl_xor(m, off, 64);
        float so = __shfl_xor(s, off, 64);
        float mn = fmaxf(m, mo);
        s = s * EXP2(m - mn) + so * EXP2(mo - mn);
        m = mn;
      }
      if (lane < 16) {
        int i = rowbase + rs * 16 + lane;
        Pcur[(tbl * NPARTS + part) * NPT + i] = make_float2(m, s);
      }
    }

    __syncthreads();   // protect frag reuse if multiple L per launch
  }
}

// reduce1: finalize last-iter partials, per-row contribution, per-block partial sums
__global__ __launch_bounds__(256) void reduce1(const float2* P, float* R1) {
  int u = blockIdx.x * 256 + threadIdx.x;   // 0..8191
  int b = u >> 12, i = u & 4095;
  float Ls[4];
#pragma unroll
  for (int t = 0; t < 4; ++t) {
    int tbl = t * 2 + b;
    float2 q0 = P[(tbl * NPARTS + 0) * NPT + i];
    float2 q1 = P[(tbl * NPARTS + 1) * NPT + i];
    float2 q2 = P[(tbl * NPARTS + 2) * NPT + i];
    float2 q3 = P[(tbl * NPARTS + 3) * NPT + i];
    float M = fmaxf(fmaxf(q0.x, q1.x), fmaxf(q2.x, q3.x));
    float S = q0.y * EXP2(q0.x - M) + q1.y * EXP2(q1.x - M)
            + q2.y * EXP2(q2.x - M) + q3.y * EXP2(q3.x - M);
    Ls[t] = M + LOG2(S);
  }
  // (b_x - a_x) + (a_y - b_y) = -eps*ln2*((L0 - L2) + (L1 - L3))
  float acc = (Ls[0] - Ls[2]) + (Ls[1] - Ls[3]);
#pragma unroll
  for (int off = 32; off >= 1; off >>= 1) acc += __shfl_xor(acc, off, 64);
  __shared__ float red[4];
  int wave = threadIdx.x >> 6, lane = threadIdx.x & 63;
  if (lane == 0) red[wave] = acc;
  __syncthreads();
  if (threadIdx.x == 0)
    R1[blockIdx.x] = red[0] + red[1] + red[2] + red[3];
}

__global__ __launch_bounds__(64) void reduce2(const float* R1, float* out) {
  float a = (threadIdx.x < 32) ? R1[threadIdx.x] : 0.0f;
#pragma unroll
  for (int off = 32; off >= 1; off >>= 1) a += __shfl_xor(a, off, 64);
  if (threadIdx.x == 0)
    out[0] = a * (-0.0025f * KLN2 / 4096.0f);
}

extern "C" void kernel_launch(void* const* d_in, const int* in_sizes, int n_in,
                              void* d_out, int out_size, void* d_ws, size_t ws_size,
                              hipStream_t stream) {
  const float* x = (const float*)d_in[0];   // true_data
  const float* y = (const float*)d_in[1];   // particles
  float* out = (float*)d_out;
  float* W = (float*)d_ws;

  // partials: 8 tbl x 4 parts x 4096 x float2 = 1 MB per set
  KArgs K;
  K.x = x; K.y = y;
  K.P0 = (float2*)W;
  K.P1 = (float2*)(W + 262144);
  K.F0 = W + 524288;
  K.F1 = W + 557056;
  float* R1buf = W + 589824;                // 32 floats

  for (int L = 0; L < NITER; ++L)
    sinkhorn_iters<<<dim3(GRID), dim3(BLOCK), 0, stream>>>(K, L, L + 1);
  // last iteration L=10 wrote Pbuf[10&1] = P0
  reduce1<<<32, 256, 0, stream>>>(K.P0, R1buf);
  reduce2<<<1, 64, 0, stream>>>(R1buf, out);
}